// Round 6
// baseline (10955.823 us; speedup 1.0000x reference)
//
#include <hip/hip_runtime.h>
#include <cstdint>
#include <cstddef>

typedef unsigned short u16;
typedef unsigned int   u32;
typedef __bf16 bf16x8 __attribute__((ext_vector_type(8)));
typedef float  f32x4  __attribute__((ext_vector_type(4)));

// ---------- bf16 helpers (RNE) ----------
__device__ __forceinline__ float bf2f(u16 u) {
  union { u32 i; float f; } v; v.i = ((u32)u) << 16; return v.f;
}
__device__ __forceinline__ u16 f2bf(float f) {
  union { float f; u32 i; } v; v.f = f;
  u32 r = v.i + 0x7fffu + ((v.i >> 16) & 1u);
  return (u16)(r >> 16);
}
__device__ __forceinline__ void unpack8(uint4 raw, float* v) {
  v[0]=bf2f(raw.x&0xffff); v[1]=bf2f(raw.x>>16);
  v[2]=bf2f(raw.y&0xffff); v[3]=bf2f(raw.y>>16);
  v[4]=bf2f(raw.z&0xffff); v[5]=bf2f(raw.z>>16);
  v[6]=bf2f(raw.w&0xffff); v[7]=bf2f(raw.w>>16);
}
__device__ __forceinline__ uint4 pack8(const float* v) {
  uint4 r;
  r.x = (u32)f2bf(v[0]) | ((u32)f2bf(v[1])<<16);
  r.y = (u32)f2bf(v[2]) | ((u32)f2bf(v[3])<<16);
  r.z = (u32)f2bf(v[4]) | ((u32)f2bf(v[5])<<16);
  r.w = (u32)f2bf(v[6]) | ((u32)f2bf(v[7])<<16);
  return r;
}
__device__ __forceinline__ void gload16(const void* g, void* l) {
  __builtin_amdgcn_global_load_lds((const __attribute__((address_space(1))) void*)g,
                                   (__attribute__((address_space(3))) void*)l, 16, 0, 0);
}

// ---------- load 8 consecutive elems as f32, from f32 or bf16 source ----------
template<typename T>
__device__ __forceinline__ void load8(const T* p, float* v);
template<> __device__ __forceinline__ void load8<float>(const float* p, float* v) {
  const float4 a = ((const float4*)p)[0];
  const float4 b = ((const float4*)p)[1];
  v[0]=a.x; v[1]=a.y; v[2]=a.z; v[3]=a.w;
  v[4]=b.x; v[5]=b.y; v[6]=b.z; v[7]=b.w;
}
template<> __device__ __forceinline__ void load8<u16>(const u16* p, float* v) {
  unpack8(*(const uint4*)p, v);
}

// ---------- LayerNorm + FWHT(2048), one row per block; out bf16 ----------
template<typename T>
__global__ __launch_bounds__(256) void ln_fwht_k(const T* __restrict__ X,
    const float* __restrict__ G, const float* __restrict__ Bt, u16* __restrict__ O) {
  __shared__ float buf[2048];
  __shared__ float red[8];
  const int tid = threadIdx.x;
  const int lane = tid & 63, wave = tid >> 6;
  const size_t base = (size_t)blockIdx.x * 2048;
  float v[8]; load8(X + base + tid*8, v);
  float s = 0.f, s2 = 0.f;
  for (int j = 0; j < 8; ++j) { s += v[j]; s2 += v[j]*v[j]; }
  for (int m = 1; m < 64; m <<= 1) { s += __shfl_xor(s, m, 64); s2 += __shfl_xor(s2, m, 64); }
  if (lane == 0) { red[wave] = s; red[4 + wave] = s2; }
  __syncthreads();
  s  = red[0] + red[1] + red[2] + red[3];
  s2 = red[4] + red[5] + red[6] + red[7];
  const float mu = s * (1.f/2048.f);
  const float rstd = rsqrtf(s2 * (1.f/2048.f) - mu*mu + 1e-5f);
  float g[8], bb[8];
  load8(G + tid*8, g); load8(Bt + tid*8, bb);
  for (int j = 0; j < 8; ++j) buf[tid*8 + j] = (v[j] - mu) * rstd * g[j] + bb[j];
  __syncthreads();
  for (int h = 1; h < 2048; h <<= 1) {
    for (int p = 0; p < 4; ++p) {
      const int idx = p*256 + tid;
      const int i = ((idx & ~(h-1)) << 1) | (idx & (h-1));
      const float a = buf[i], c = buf[i + h];
      buf[i] = a + c; buf[i + h] = a - c;
    }
    __syncthreads();
  }
  float o[8];
  for (int j = 0; j < 8; ++j) o[j] = buf[tid*8 + j] * 0.02209708691207961f; // 1/sqrt(2048)
  *(uint4*)&O[base + tid*8] = pack8(o);
}

// ---------- in-place FWHT<N> on bf16 rows ----------
template<int N>
__global__ __launch_bounds__(256) void fwht_ip(u16* __restrict__ D) {
  __shared__ float buf[N];
  const int tid = threadIdx.x;
  const size_t base = (size_t)blockIdx.x * N;
  constexpr int V8 = N / (8*256);
  for (int i = 0; i < V8; ++i) {
    uint4 raw = *(const uint4*)&D[base + (i*256 + tid)*8];
    float v[8]; unpack8(raw, v);
    for (int j = 0; j < 8; ++j) buf[(i*256 + tid)*8 + j] = v[j];
  }
  __syncthreads();
  constexpr int PAIRS = N / 2 / 256;
  for (int h = 1; h < N; h <<= 1) {
    for (int p = 0; p < PAIRS; ++p) {
      const int idx = p*256 + tid;
      const int i = ((idx & ~(h-1)) << 1) | (idx & (h-1));
      const float a = buf[i], c = buf[i + h];
      buf[i] = a + c; buf[i + h] = a - c;
    }
    __syncthreads();
  }
  const float sc = rsqrtf((float)N);
  for (int i = 0; i < V8; ++i) {
    float v[8];
    for (int j = 0; j < 8; ++j) v[j] = buf[(i*256 + tid)*8 + j] * sc;
    *(uint4*)&D[base + (i*256 + tid)*8] = pack8(v);
  }
}

// ---------- m97-style GEMM with fused int8-dequant B ----------
// C[m][n] = (sum_k A_bf16[m][k] * Qint[n][k]) * S[n]  (+bias, gelu, +res)
// A [M,K] bf16; Qint [N,K] int32 (|q|<=127, bf16-exact); S [N] f32.
// C: bf16 (outf32=0) or f32 (outf32=1), ldc row stride.
__global__ __launch_bounds__(256) void gemm_btq(
    const u16* __restrict__ A, const int* __restrict__ Qint, const float* __restrict__ S,
    void* __restrict__ C, int ldc, int M, int N, int K,
    const float* __restrict__ bias, const float* __restrict__ resf,
    const u16* __restrict__ resb, int dogelu, int outf32)
{
  __shared__ alignas(16) u16 sA[128*32];
  __shared__ alignas(16) u16 sB[128*32];
  const int tid = threadIdx.x;
  const int lane = tid & 63, wave = tid >> 6;
  const int quad = lane >> 4, l16 = lane & 15;
  const int wm = wave & 1, wn = wave >> 1;
  const long tM = (long)blockIdx.x * 128;
  const long tN = (long)blockIdx.y * 128;
  const int sr = lane >> 2;          // row within 16-row A staging chunk
  const int scol = (lane & 3) * 8;   // col (elements)
  f32x4 acc[4][4] = {};
  for (int k0 = 0; k0 < K; k0 += 32) {
    // A tile: 8 chunks x 512 elems via global_load_lds (16B/lane)
    for (int i = 0; i < 2; ++i) {
      const int chunk = i*4 + wave;
      const int r = chunk*16 + sr;
      gload16(A + (size_t)(tM + r)*K + k0 + scol, &sA[chunk*512]);
    }
    // B tile: 128x32 int32 -> bf16 (exact) via VGPR
    for (int i = 0; i < 4; ++i) {
      const int idx = i*256 + tid;          // 0..1023, covers 4096 ints
      const int r  = idx >> 3;              // B row 0..127
      const int c4 = (idx & 7) * 4;         // k sub-col (ints)
      const int4 q = *(const int4*)(Qint + (size_t)(tN + r)*K + k0 + c4);
      uint2 w;
      w.x = (u32)f2bf((float)q.x) | ((u32)f2bf((float)q.y) << 16);
      w.y = (u32)f2bf((float)q.z) | ((u32)f2bf((float)q.w) << 16);
      *(uint2*)&sB[r*32 + c4] = w;
    }
    __syncthreads();
    bf16x8 af[4], bq[4];
    for (int t = 0; t < 4; ++t) af[t] = *(const bf16x8*)&sA[(wm*64 + t*16 + l16)*32 + quad*8];
    for (int t = 0; t < 4; ++t) bq[t] = *(const bf16x8*)&sB[(wn*64 + t*16 + l16)*32 + quad*8];
    for (int im = 0; im < 4; ++im)
      for (int in = 0; in < 4; ++in)
        acc[im][in] = __builtin_amdgcn_mfma_f32_16x16x32_bf16(af[im], bq[in], acc[im][in], 0, 0, 0);
    __syncthreads();
  }
  for (int in = 0; in < 4; ++in) {
    const long col = tN + wn*64 + in*16 + l16;
    const float sc = S[col];
    const float bv = bias ? bias[col] : 0.f;
    for (int im = 0; im < 4; ++im) {
      const long row0 = tM + wm*64 + im*16 + quad*4;
      for (int r = 0; r < 4; ++r) {
        float v = acc[im][in][r] * sc + bv;
        if (dogelu) v = 0.5f * v * (1.f + erff(v * 0.7071067811865475f));
        const size_t off = (size_t)(row0 + r)*ldc + col;
        if (resf) v += resf[off];
        if (resb) v += bf2f(resb[off]);
        if (outf32) ((float*)C)[off] = v;
        else        ((u16*)C)[off]   = f2bf(v);
      }
    }
  }
}

// ---------- fused MFMA attention: QKV packed [4096, 6144] bf16, O [4096, 2048] bf16 ----------
__global__ __launch_bounds__(256) void attn_k(const u16* __restrict__ QKV, u16* __restrict__ O)
{
  __shared__ alignas(16) u16 sKV[16384];  // K tile [128][128], then V^T tile [d=128][kv=128]
  __shared__ alignas(16) u16 sP[16384];   // Q tile [128][128] at start, then per-wave P [32][128]
  const int tid = threadIdx.x;
  const int lane = tid & 63, wave = tid >> 6;
  const int quad = lane >> 4, l16 = lane & 15;
  const int qt = blockIdx.x;        // 0..7
  const int bh = blockIdx.y;        // 0..63
  const int b = bh >> 4, h = bh & 15;
  const size_t rb = (size_t)b * 1024;
  const u16* Qg = QKV + (rb + (size_t)qt*128)*6144 + h*128;
  const u16* Kg = QKV + rb*6144 + 2048 + h*128;
  const u16* Vg = QKV + rb*6144 + 4096 + h*128;

  for (int c = 0; c < 8; ++c) {
    const int chunk = c*4 + wave;        // 0..31, 1 KiB = 4 rows
    const int r = chunk*4 + quad;
    gload16(Qg + (size_t)r*6144 + l16*8, &sP[chunk*512]);
  }
  __syncthreads();
  bf16x8 aq[2][4];
  for (int im = 0; im < 2; ++im)
    for (int kk = 0; kk < 4; ++kk)
      aq[im][kk] = *(const bf16x8*)&sP[(wave*32 + im*16 + l16)*128 + kk*32 + quad*8];

  float mrun[2][4], lrun[2][4];
  f32x4 oacc[2][8] = {};
  for (int im = 0; im < 2; ++im)
    for (int r = 0; r < 4; ++r) { mrun[im][r] = -1e30f; lrun[im][r] = 0.f; }

  for (int kt = 0; kt < 8; ++kt) {
    __syncthreads();
    for (int c = 0; c < 8; ++c) {
      const int chunk = c*4 + wave;
      const int r = chunk*4 + quad;
      gload16(Kg + (size_t)(kt*128 + r)*6144 + l16*8, &sKV[chunk*512]);
    }
    __syncthreads();
    f32x4 sf[2][8] = {};
    for (int kk = 0; kk < 4; ++kk)
      for (int jn = 0; jn < 8; ++jn) {
        const bf16x8 bk = *(const bf16x8*)&sKV[(jn*16 + l16)*128 + kk*32 + quad*8];
        sf[0][jn] = __builtin_amdgcn_mfma_f32_16x16x32_bf16(aq[0][kk], bk, sf[0][jn], 0, 0, 0);
        sf[1][jn] = __builtin_amdgcn_mfma_f32_16x16x32_bf16(aq[1][kk], bk, sf[1][jn], 0, 0, 0);
      }
    const float scale = 0.08838834764831845f;   // 1/sqrt(128)
    for (int im = 0; im < 2; ++im)
      for (int r = 0; r < 4; ++r) {
        float mx = -1e30f;
        for (int jn = 0; jn < 8; ++jn) mx = fmaxf(mx, sf[im][jn][r] * scale);
        for (int m = 1; m < 16; m <<= 1) mx = fmaxf(mx, __shfl_xor(mx, m, 64));
        const float mold = mrun[im][r];
        const float mnew = fmaxf(mold, mx);
        const float alpha = __expf(mold - mnew);
        float ls = 0.f;
        for (int jn = 0; jn < 8; ++jn) {
          const float p = __expf(sf[im][jn][r] * scale - mnew);
          ls += p;
          sP[wave*4096 + (im*16 + quad*4 + r)*128 + jn*16 + l16] = f2bf(p);
        }
        for (int m = 1; m < 16; m <<= 1) ls += __shfl_xor(ls, m, 64);
        lrun[im][r] = lrun[im][r]*alpha + ls;
        mrun[im][r] = mnew;
        for (int od = 0; od < 8; ++od) oacc[im][od][r] *= alpha;
      }
    __syncthreads();
    for (int c = 0; c < 8; ++c) {
      const int chunk = c*256 + tid;       // 0..2047
      const int kv = chunk >> 4;
      const int db = (chunk & 15) * 8;
      const uint4 raw = *(const uint4*)(Vg + (size_t)(kt*128 + kv)*6144 + db);
      const u32 w0[4] = {raw.x, raw.y, raw.z, raw.w};
      for (int j = 0; j < 4; ++j) {
        sKV[(db + 2*j  )*128 + kv] = (u16)(w0[j] & 0xffff);
        sKV[(db + 2*j+1)*128 + kv] = (u16)(w0[j] >> 16);
      }
    }
    __syncthreads();
    for (int kk = 0; kk < 4; ++kk) {
      const bf16x8 ap0 = *(const bf16x8*)&sP[wave*4096 + (     l16)*128 + kk*32 + quad*8];
      const bf16x8 ap1 = *(const bf16x8*)&sP[wave*4096 + (16 + l16)*128 + kk*32 + quad*8];
      for (int od = 0; od < 8; ++od) {
        const bf16x8 bv = *(const bf16x8*)&sKV[(od*16 + l16)*128 + kk*32 + quad*8];
        oacc[0][od] = __builtin_amdgcn_mfma_f32_16x16x32_bf16(ap0, bv, oacc[0][od], 0, 0, 0);
        oacc[1][od] = __builtin_amdgcn_mfma_f32_16x16x32_bf16(ap1, bv, oacc[1][od], 0, 0, 0);
      }
    }
  }
  for (int im = 0; im < 2; ++im)
    for (int r = 0; r < 4; ++r) {
      const float inv = 1.f / lrun[im][r];
      const size_t row = rb + (size_t)qt*128 + wave*32 + im*16 + quad*4 + r;
      for (int od = 0; od < 8; ++od)
        O[row*2048 + h*128 + od*16 + l16] = f2bf(oacc[im][od][r] * inv);
    }
}

extern "C" void kernel_launch(void* const* d_in, const int* in_sizes, int n_in,
                              void* d_out, int out_size, void* d_ws, size_t ws_size,
                              hipStream_t stream) {
  const float* x    = (const float*)d_in[0];
  const float* ln1g = (const float*)d_in[1];
  const float* ln1b = (const float*)d_in[2];
  const float* ln2g = (const float*)d_in[3];
  const float* ln2b = (const float*)d_in[4];
  const int* Qq  = (const int*)d_in[5];  const float* sq  = (const float*)d_in[6];
  const int* Qk  = (const int*)d_in[7];  const float* sk  = (const float*)d_in[8];
  const int* Qv  = (const int*)d_in[9];  const float* sv  = (const float*)d_in[10];
  const int* Qo  = (const int*)d_in[11]; const float* so  = (const float*)d_in[12];
  const int* Qf1 = (const int*)d_in[13]; const float* sf1 = (const float*)d_in[14];
  const float* bf1 = (const float*)d_in[15];
  const int* Qf2 = (const int*)d_in[16]; const float* sf2 = (const float*)d_in[17];
  const float* bf2 = (const float*)d_in[18];

  // arena (u16 elems), exactly 96 MiB = confirmed-available ws:
  //   A  [0          .. 8,388,608)  : XH1 -> ATT -> XH2           (16 MiB)
  //   B  [8,388,608  .. 33,554,432) : QKV [4096,6144]             (48 MiB)
  //   FF [8,388,608  .. 41,943,040) : [4096,8192] (after attn)    (64 MiB)
  //   X1 [41,943,040 .. 50,331,648) : [4096,2048]                 (16 MiB)
  u16* A   = (u16*)d_ws;
  u16* QKV = A + 8388608;
  u16* FF  = QKV;                       // reuses QKV region + Wf area
  u16* X1  = A + 41943040;
  if (ws_size < (size_t)100663296) return;   // guard (signals via poisoned d_out)

  // 1) LN1 + FWHT (f32 x -> bf16 XH1)
  ln_fwht_k<float><<<4096, 256, 0, stream>>>(x, ln1g, ln1b, A);

  // 2) Q/K/V projections (fused dequant) into column slices of QKV [4096,6144]
  gemm_btq<<<dim3(32,16), 256, 0, stream>>>(A, Qq, sq, QKV + 0,    6144, 4096, 2048, 2048, nullptr, nullptr, nullptr, 0, 0);
  gemm_btq<<<dim3(32,16), 256, 0, stream>>>(A, Qk, sk, QKV + 2048, 6144, 4096, 2048, 2048, nullptr, nullptr, nullptr, 0, 0);
  gemm_btq<<<dim3(32,16), 256, 0, stream>>>(A, Qv, sv, QKV + 4096, 6144, 4096, 2048, 2048, nullptr, nullptr, nullptr, 0, 0);

  // 3) attention -> ATT (A region)
  attn_k<<<dim3(8, 64), 256, 0, stream>>>(QKV, A);

  // 4) FWHT(2048) in-place on ATT
  fwht_ip<2048><<<4096, 256, 0, stream>>>(A);

  // 5) O-proj + residual(x, f32) -> X1 (bf16)
  gemm_btq<<<dim3(32,16), 256, 0, stream>>>(A, Qo, so, X1, 2048, 4096, 2048, 2048, nullptr, x, nullptr, 0, 0);

  // 6) LN2 + FWHT: X1 -> XH2 (A region)
  ln_fwht_k<u16><<<4096, 256, 0, stream>>>(X1, ln2g, ln2b, A);

  // 7) FF1 + bias + exact GELU -> FF (bf16)
  gemm_btq<<<dim3(32,64), 256, 0, stream>>>(A, Qf1, sf1, FF, 8192, 4096, 8192, 2048, bf1, nullptr, nullptr, 1, 0);

  // 8) FWHT(8192) in-place on FF
  fwht_ip<8192><<<4096, 256, 0, stream>>>(FF);

  // 9) FF2 + bias + residual(X1) -> d_out as FLOAT32
  gemm_btq<<<dim3(32,16), 256, 0, stream>>>(FF, Qf2, sf2, d_out, 2048, 4096, 2048, 8192, bf2, nullptr, X1, 0, 1);
}

// Round 7
// 1547.511 us; speedup vs baseline: 7.0796x; 7.0796x over previous
//
#include <hip/hip_runtime.h>
#include <cstdint>
#include <cstddef>

typedef unsigned short u16;
typedef unsigned int   u32;
typedef __bf16 bf16x8 __attribute__((ext_vector_type(8)));
typedef float  f32x4  __attribute__((ext_vector_type(4)));

// ---------- bf16 helpers (RNE) ----------
__device__ __forceinline__ float bf2f(u16 u) {
  union { u32 i; float f; } v; v.i = ((u32)u) << 16; return v.f;
}
__device__ __forceinline__ u16 f2bf(float f) {
  union { float f; u32 i; } v; v.f = f;
  u32 r = v.i + 0x7fffu + ((v.i >> 16) & 1u);
  return (u16)(r >> 16);
}
__device__ __forceinline__ void unpack8(uint4 raw, float* v) {
  v[0]=bf2f(raw.x&0xffff); v[1]=bf2f(raw.x>>16);
  v[2]=bf2f(raw.y&0xffff); v[3]=bf2f(raw.y>>16);
  v[4]=bf2f(raw.z&0xffff); v[5]=bf2f(raw.z>>16);
  v[6]=bf2f(raw.w&0xffff); v[7]=bf2f(raw.w>>16);
}
__device__ __forceinline__ uint4 pack8(const float* v) {
  uint4 r;
  r.x = (u32)f2bf(v[0]) | ((u32)f2bf(v[1])<<16);
  r.y = (u32)f2bf(v[2]) | ((u32)f2bf(v[3])<<16);
  r.z = (u32)f2bf(v[4]) | ((u32)f2bf(v[5])<<16);
  r.w = (u32)f2bf(v[6]) | ((u32)f2bf(v[7])<<16);
  return r;
}
__device__ __forceinline__ void gload16(const void* g, void* l) {
  __builtin_amdgcn_global_load_lds((const __attribute__((address_space(1))) void*)g,
                                   (__attribute__((address_space(3))) void*)l, 16, 0, 0);
}

// ---------- load 8 consecutive elems as f32, from f32 or bf16 source ----------
template<typename T>
__device__ __forceinline__ void load8(const T* p, float* v);
template<> __device__ __forceinline__ void load8<float>(const float* p, float* v) {
  const float4 a = ((const float4*)p)[0];
  const float4 b = ((const float4*)p)[1];
  v[0]=a.x; v[1]=a.y; v[2]=a.z; v[3]=a.w;
  v[4]=b.x; v[5]=b.y; v[6]=b.z; v[7]=b.w;
}
template<> __device__ __forceinline__ void load8<u16>(const u16* p, float* v) {
  unpack8(*(const uint4*)p, v);
}

// ---------- LayerNorm + FWHT(2048), one row per block; out bf16 ----------
template<typename T>
__global__ __launch_bounds__(256) void ln_fwht_k(const T* __restrict__ X,
    const float* __restrict__ G, const float* __restrict__ Bt, u16* __restrict__ O) {
  __shared__ float buf[2048];
  __shared__ float red[8];
  const int tid = threadIdx.x;
  const int lane = tid & 63, wave = tid >> 6;
  const size_t base = (size_t)blockIdx.x * 2048;
  float v[8]; load8(X + base + tid*8, v);
  float s = 0.f, s2 = 0.f;
  for (int j = 0; j < 8; ++j) { s += v[j]; s2 += v[j]*v[j]; }
  for (int m = 1; m < 64; m <<= 1) { s += __shfl_xor(s, m, 64); s2 += __shfl_xor(s2, m, 64); }
  if (lane == 0) { red[wave] = s; red[4 + wave] = s2; }
  __syncthreads();
  s  = red[0] + red[1] + red[2] + red[3];
  s2 = red[4] + red[5] + red[6] + red[7];
  const float mu = s * (1.f/2048.f);
  const float rstd = rsqrtf(s2 * (1.f/2048.f) - mu*mu + 1e-5f);
  float g[8], bb[8];
  load8(G + tid*8, g); load8(Bt + tid*8, bb);
  for (int j = 0; j < 8; ++j) buf[tid*8 + j] = (v[j] - mu) * rstd * g[j] + bb[j];
  __syncthreads();
  for (int h = 1; h < 2048; h <<= 1) {
    for (int p = 0; p < 4; ++p) {
      const int idx = p*256 + tid;
      const int i = ((idx & ~(h-1)) << 1) | (idx & (h-1));
      const float a = buf[i], c = buf[i + h];
      buf[i] = a + c; buf[i + h] = a - c;
    }
    __syncthreads();
  }
  float o[8];
  for (int j = 0; j < 8; ++j) o[j] = buf[tid*8 + j] * 0.02209708691207961f; // 1/sqrt(2048)
  *(uint4*)&O[base + tid*8] = pack8(o);
}

// ---------- in-place FWHT<N> on bf16 rows ----------
template<int N>
__global__ __launch_bounds__(256) void fwht_ip(u16* __restrict__ D) {
  __shared__ float buf[N];
  const int tid = threadIdx.x;
  const size_t base = (size_t)blockIdx.x * N;
  constexpr int V8 = N / (8*256);
  for (int i = 0; i < V8; ++i) {
    uint4 raw = *(const uint4*)&D[base + (i*256 + tid)*8];
    float v[8]; unpack8(raw, v);
    for (int j = 0; j < 8; ++j) buf[(i*256 + tid)*8 + j] = v[j];
  }
  __syncthreads();
  constexpr int PAIRS = N / 2 / 256;
  for (int h = 1; h < N; h <<= 1) {
    for (int p = 0; p < PAIRS; ++p) {
      const int idx = p*256 + tid;
      const int i = ((idx & ~(h-1)) << 1) | (idx & (h-1));
      const float a = buf[i], c = buf[i + h];
      buf[i] = a + c; buf[i + h] = a - c;
    }
    __syncthreads();
  }
  const float sc = rsqrtf((float)N);
  for (int i = 0; i < V8; ++i) {
    float v[8];
    for (int j = 0; j < 8; ++j) v[j] = buf[(i*256 + tid)*8 + j] * sc;
    *(uint4*)&D[base + (i*256 + tid)*8] = pack8(v);
  }
}

// ---------- m97-style GEMM with fused int8-dequant B ----------
// C[m][n] = (sum_k A_bf16[m][k] * Qint[n][k]) * S[n]  (+bias, gelu, +res)
// A [M,K] bf16; Qint [N,K] int32 (|q|<=127, bf16-exact); S [N] f32.
// C: bf16 (outf32=0) or f32 (outf32=1), ldc row stride.
// __launch_bounds__(256,2): 2 waves/EU -> ~256 VGPR budget/wave. Round-6 PMC
// showed acc spilling to scratch under the default budget (VGPR_Count=76,
// WRITE_SIZE 8.45 GB/dispatch == blocks*threads*iters*256B, MfmaUtil 1.5%).
__global__ __launch_bounds__(256, 2) void gemm_btq(
    const u16* __restrict__ A, const int* __restrict__ Qint, const float* __restrict__ S,
    void* __restrict__ C, int ldc, int M, int N, int K,
    const float* __restrict__ bias, const float* __restrict__ resf,
    const u16* __restrict__ resb, int dogelu, int outf32)
{
  __shared__ alignas(16) u16 sA[128*32];
  __shared__ alignas(16) u16 sB[128*32];
  const int tid = threadIdx.x;
  const int lane = tid & 63, wave = tid >> 6;
  const int quad = lane >> 4, l16 = lane & 15;
  const int wm = wave & 1, wn = wave >> 1;
  const long tM = (long)blockIdx.x * 128;
  const long tN = (long)blockIdx.y * 128;
  const int sr = lane >> 2;          // row within 16-row A staging chunk
  const int scol = (lane & 3) * 8;   // col (elements)
  f32x4 acc[4][4] = {};
  for (int k0 = 0; k0 < K; k0 += 32) {
    // A tile: 8 chunks x 512 elems via global_load_lds (16B/lane)
#pragma unroll
    for (int i = 0; i < 2; ++i) {
      const int chunk = i*4 + wave;
      const int r = chunk*16 + sr;
      gload16(A + (size_t)(tM + r)*K + k0 + scol, &sA[chunk*512]);
    }
    // B tile: 128x32 int32 -> bf16 (exact) via VGPR
#pragma unroll
    for (int i = 0; i < 4; ++i) {
      const int idx = i*256 + tid;          // 0..1023, covers 4096 ints
      const int r  = idx >> 3;              // B row 0..127
      const int c4 = (idx & 7) * 4;         // k sub-col (ints)
      const int4 q = *(const int4*)(Qint + (size_t)(tN + r)*K + k0 + c4);
      uint2 w;
      w.x = (u32)f2bf((float)q.x) | ((u32)f2bf((float)q.y) << 16);
      w.y = (u32)f2bf((float)q.z) | ((u32)f2bf((float)q.w) << 16);
      *(uint2*)&sB[r*32 + c4] = w;
    }
    __syncthreads();
    bf16x8 af[4], bq[4];
#pragma unroll
    for (int t = 0; t < 4; ++t) af[t] = *(const bf16x8*)&sA[(wm*64 + t*16 + l16)*32 + quad*8];
#pragma unroll
    for (int t = 0; t < 4; ++t) bq[t] = *(const bf16x8*)&sB[(wn*64 + t*16 + l16)*32 + quad*8];
#pragma unroll
    for (int im = 0; im < 4; ++im)
#pragma unroll
      for (int in = 0; in < 4; ++in)
        acc[im][in] = __builtin_amdgcn_mfma_f32_16x16x32_bf16(af[im], bq[in], acc[im][in], 0, 0, 0);
    __syncthreads();
  }
#pragma unroll
  for (int in = 0; in < 4; ++in) {
    const long col = tN + wn*64 + in*16 + l16;
    const float sc = S[col];
    const float bv = bias ? bias[col] : 0.f;
#pragma unroll
    for (int im = 0; im < 4; ++im) {
      const long row0 = tM + wm*64 + im*16 + quad*4;
#pragma unroll
      for (int r = 0; r < 4; ++r) {
        float v = acc[im][in][r] * sc + bv;
        if (dogelu) v = 0.5f * v * (1.f + erff(v * 0.7071067811865475f));
        const size_t off = (size_t)(row0 + r)*ldc + col;
        if (resf) v += resf[off];
        if (resb) v += bf2f(resb[off]);
        if (outf32) ((float*)C)[off] = v;
        else        ((u16*)C)[off]   = f2bf(v);
      }
    }
  }
}

// ---------- fused MFMA attention: QKV packed [4096, 6144] bf16, O [4096, 2048] bf16 ----------
__global__ __launch_bounds__(256, 2) void attn_k(const u16* __restrict__ QKV, u16* __restrict__ O)
{
  __shared__ alignas(16) u16 sKV[16384];  // K tile [128][128], then V^T tile [d=128][kv=128]
  __shared__ alignas(16) u16 sP[16384];   // Q tile [128][128] at start, then per-wave P [32][128]
  const int tid = threadIdx.x;
  const int lane = tid & 63, wave = tid >> 6;
  const int quad = lane >> 4, l16 = lane & 15;
  const int qt = blockIdx.x;        // 0..7
  const int bh = blockIdx.y;        // 0..63
  const int b = bh >> 4, h = bh & 15;
  const size_t rb = (size_t)b * 1024;
  const u16* Qg = QKV + (rb + (size_t)qt*128)*6144 + h*128;
  const u16* Kg = QKV + rb*6144 + 2048 + h*128;
  const u16* Vg = QKV + rb*6144 + 4096 + h*128;

  for (int c = 0; c < 8; ++c) {
    const int chunk = c*4 + wave;        // 0..31, 1 KiB = 4 rows
    const int r = chunk*4 + quad;
    gload16(Qg + (size_t)r*6144 + l16*8, &sP[chunk*512]);
  }
  __syncthreads();
  bf16x8 aq[2][4];
  for (int im = 0; im < 2; ++im)
    for (int kk = 0; kk < 4; ++kk)
      aq[im][kk] = *(const bf16x8*)&sP[(wave*32 + im*16 + l16)*128 + kk*32 + quad*8];

  float mrun[2][4], lrun[2][4];
  f32x4 oacc[2][8] = {};
  for (int im = 0; im < 2; ++im)
    for (int r = 0; r < 4; ++r) { mrun[im][r] = -1e30f; lrun[im][r] = 0.f; }

  for (int kt = 0; kt < 8; ++kt) {
    __syncthreads();
    for (int c = 0; c < 8; ++c) {
      const int chunk = c*4 + wave;
      const int r = chunk*4 + quad;
      gload16(Kg + (size_t)(kt*128 + r)*6144 + l16*8, &sKV[chunk*512]);
    }
    __syncthreads();
    f32x4 sf[2][8] = {};
#pragma unroll
    for (int kk = 0; kk < 4; ++kk)
#pragma unroll
      for (int jn = 0; jn < 8; ++jn) {
        const bf16x8 bk = *(const bf16x8*)&sKV[(jn*16 + l16)*128 + kk*32 + quad*8];
        sf[0][jn] = __builtin_amdgcn_mfma_f32_16x16x32_bf16(aq[0][kk], bk, sf[0][jn], 0, 0, 0);
        sf[1][jn] = __builtin_amdgcn_mfma_f32_16x16x32_bf16(aq[1][kk], bk, sf[1][jn], 0, 0, 0);
      }
    const float scale = 0.08838834764831845f;   // 1/sqrt(128)
#pragma unroll
    for (int im = 0; im < 2; ++im)
#pragma unroll
      for (int r = 0; r < 4; ++r) {
        float mx = -1e30f;
        for (int jn = 0; jn < 8; ++jn) mx = fmaxf(mx, sf[im][jn][r] * scale);
        for (int m = 1; m < 16; m <<= 1) mx = fmaxf(mx, __shfl_xor(mx, m, 64));
        const float mold = mrun[im][r];
        const float mnew = fmaxf(mold, mx);
        const float alpha = __expf(mold - mnew);
        float ls = 0.f;
        for (int jn = 0; jn < 8; ++jn) {
          const float p = __expf(sf[im][jn][r] * scale - mnew);
          ls += p;
          sP[wave*4096 + (im*16 + quad*4 + r)*128 + jn*16 + l16] = f2bf(p);
        }
        for (int m = 1; m < 16; m <<= 1) ls += __shfl_xor(ls, m, 64);
        lrun[im][r] = lrun[im][r]*alpha + ls;
        mrun[im][r] = mnew;
        for (int od = 0; od < 8; ++od) oacc[im][od][r] *= alpha;
      }
    __syncthreads();
    for (int c = 0; c < 8; ++c) {
      const int chunk = c*256 + tid;       // 0..2047
      const int kv = chunk >> 4;
      const int db = (chunk & 15) * 8;
      const uint4 raw = *(const uint4*)(Vg + (size_t)(kt*128 + kv)*6144 + db);
      const u32 w0[4] = {raw.x, raw.y, raw.z, raw.w};
      for (int j = 0; j < 4; ++j) {
        sKV[(db + 2*j  )*128 + kv] = (u16)(w0[j] & 0xffff);
        sKV[(db + 2*j+1)*128 + kv] = (u16)(w0[j] >> 16);
      }
    }
    __syncthreads();
#pragma unroll
    for (int kk = 0; kk < 4; ++kk) {
      const bf16x8 ap0 = *(const bf16x8*)&sP[wave*4096 + (     l16)*128 + kk*32 + quad*8];
      const bf16x8 ap1 = *(const bf16x8*)&sP[wave*4096 + (16 + l16)*128 + kk*32 + quad*8];
#pragma unroll
      for (int od = 0; od < 8; ++od) {
        const bf16x8 bv = *(const bf16x8*)&sKV[(od*16 + l16)*128 + kk*32 + quad*8];
        oacc[0][od] = __builtin_amdgcn_mfma_f32_16x16x32_bf16(ap0, bv, oacc[0][od], 0, 0, 0);
        oacc[1][od] = __builtin_amdgcn_mfma_f32_16x16x32_bf16(ap1, bv, oacc[1][od], 0, 0, 0);
      }
    }
  }
  for (int im = 0; im < 2; ++im)
    for (int r = 0; r < 4; ++r) {
      const float inv = 1.f / lrun[im][r];
      const size_t row = rb + (size_t)qt*128 + wave*32 + im*16 + quad*4 + r;
      for (int od = 0; od < 8; ++od)
        O[row*2048 + h*128 + od*16 + l16] = f2bf(oacc[im][od][r] * inv);
    }
}

extern "C" void kernel_launch(void* const* d_in, const int* in_sizes, int n_in,
                              void* d_out, int out_size, void* d_ws, size_t ws_size,
                              hipStream_t stream) {
  const float* x    = (const float*)d_in[0];
  const float* ln1g = (const float*)d_in[1];
  const float* ln1b = (const float*)d_in[2];
  const float* ln2g = (const float*)d_in[3];
  const float* ln2b = (const float*)d_in[4];
  const int* Qq  = (const int*)d_in[5];  const float* sq  = (const float*)d_in[6];
  const int* Qk  = (const int*)d_in[7];  const float* sk  = (const float*)d_in[8];
  const int* Qv  = (const int*)d_in[9];  const float* sv  = (const float*)d_in[10];
  const int* Qo  = (const int*)d_in[11]; const float* so  = (const float*)d_in[12];
  const int* Qf1 = (const int*)d_in[13]; const float* sf1 = (const float*)d_in[14];
  const float* bf1 = (const float*)d_in[15];
  const int* Qf2 = (const int*)d_in[16]; const float* sf2 = (const float*)d_in[17];
  const float* bf2 = (const float*)d_in[18];

  // arena (u16 elems), exactly 96 MiB:
  //   A  [0          .. 8,388,608)  : XH1 -> ATT -> XH2           (16 MiB)
  //   B  [8,388,608  .. 33,554,432) : QKV [4096,6144]             (48 MiB)
  //   FF [8,388,608  .. 41,943,040) : [4096,8192] (after attn)    (64 MiB)
  //   X1 [41,943,040 .. 50,331,648) : [4096,2048]                 (16 MiB)
  u16* A   = (u16*)d_ws;
  u16* QKV = A + 8388608;
  u16* FF  = QKV;                       // reuses QKV region
  u16* X1  = A + 41943040;
  if (ws_size < (size_t)100663296) return;   // guard (signals via poisoned d_out)

  // 1) LN1 + FWHT (f32 x -> bf16 XH1)
  ln_fwht_k<float><<<4096, 256, 0, stream>>>(x, ln1g, ln1b, A);

  // 2) Q/K/V projections (fused dequant) into column slices of QKV [4096,6144]
  gemm_btq<<<dim3(32,16), 256, 0, stream>>>(A, Qq, sq, QKV + 0,    6144, 4096, 2048, 2048, nullptr, nullptr, nullptr, 0, 0);
  gemm_btq<<<dim3(32,16), 256, 0, stream>>>(A, Qk, sk, QKV + 2048, 6144, 4096, 2048, 2048, nullptr, nullptr, nullptr, 0, 0);
  gemm_btq<<<dim3(32,16), 256, 0, stream>>>(A, Qv, sv, QKV + 4096, 6144, 4096, 2048, 2048, nullptr, nullptr, nullptr, 0, 0);

  // 3) attention -> ATT (A region)
  attn_k<<<dim3(8, 64), 256, 0, stream>>>(QKV, A);

  // 4) FWHT(2048) in-place on ATT
  fwht_ip<2048><<<4096, 256, 0, stream>>>(A);

  // 5) O-proj + residual(x, f32) -> X1 (bf16)
  gemm_btq<<<dim3(32,16), 256, 0, stream>>>(A, Qo, so, X1, 2048, 4096, 2048, 2048, nullptr, x, nullptr, 0, 0);

  // 6) LN2 + FWHT: X1 -> XH2 (A region)
  ln_fwht_k<u16><<<4096, 256, 0, stream>>>(X1, ln2g, ln2b, A);

  // 7) FF1 + bias + exact GELU -> FF (bf16)
  gemm_btq<<<dim3(32,64), 256, 0, stream>>>(A, Qf1, sf1, FF, 8192, 4096, 8192, 2048, bf1, nullptr, nullptr, 1, 0);

  // 8) FWHT(8192) in-place on FF
  fwht_ip<8192><<<4096, 256, 0, stream>>>(FF);

  // 9) FF2 + bias + residual(X1) -> d_out as FLOAT32
  gemm_btq<<<dim3(32,16), 256, 0, stream>>>(FF, Qf2, sf2, d_out, 2048, 4096, 2048, 8192, bf2, nullptr, X1, 0, 1);
}